// Round 1
// baseline (212.311 us; speedup 1.0000x reference)
//
#include <hip/hip_runtime.h>
#include <math.h>

#define BB 8
#define SS 64
#define HH 256
#define NNEUR 256
#define TT (SS*HH)            // 16384
#define CL 128                // chunk length
#define NC (TT/CL)            // 128 chunks
#define OUT1 ((size_t)BB*SS*NNEUR*HH)   // 33554432

__device__ __forceinline__ float sigf(float v) {
    return 1.0f / (1.0f + expf(-v));
}

// One LIF step: acc_b = s + x_b; spike iff acc_b > thr; new s = max_b(spike ? 0 : acc_b).
// All-spike case falls out naturally (max of zeros = 0). Must be bitwise-identical
// wherever it is used (spec pass, fixup) so float-equality merge detection is valid.
__device__ __forceinline__ float lif_step(float s, const float* __restrict__ x8, float thr) {
    float best = 0.0f;
#pragma unroll
    for (int b = 0; b < BB; ++b) {
        float acc = s + x8[b];
        float cand = (acc > thr) ? 0.0f : acc;
        best = fmaxf(best, cand);
    }
    return best;
}

__device__ __forceinline__ void load_x8(const float* __restrict__ xT, int t, float* x8) {
    const float4* xp = (const float4*)(xT + (size_t)t * 8);
    float4 xa = xp[0], xb = xp[1];
    x8[0]=xa.x; x8[1]=xa.y; x8[2]=xa.z; x8[3]=xa.w;
    x8[4]=xb.x; x8[5]=xb.y; x8[6]=xb.z; x8[7]=xb.w;
}

// Pass 0: x[b][t] = sigmoid(inputs), transposed to xT[t][8] for broadcast reads.
__global__ void __launch_bounds__(256) k_prep(const float* __restrict__ in, float* __restrict__ xT) {
    int t = blockIdx.x * 256 + threadIdx.x;
    float v[BB];
#pragma unroll
    for (int b = 0; b < BB; ++b) v[b] = sigf(in[(size_t)b*TT + t]);
    float4* o = (float4*)(xT + (size_t)t * 8);
    o[0] = make_float4(v[0], v[1], v[2], v[3]);
    o[1] = make_float4(v[4], v[5], v[6], v[7]);
}

// Speculative chunk scan. block = chunk, thread = neuron.
// Round A: guess==null, states==null -> only chunk finals from guess 0.
// Round B: guess=finalA, states!=null -> store pre-state trajectory [N][T].
__global__ void __launch_bounds__(256) k_spec(const float* __restrict__ xT,
                                              const float* __restrict__ threshes,
                                              const float* __restrict__ acc0,
                                              const float* __restrict__ guess,
                                              float* __restrict__ states,
                                              float* __restrict__ chunkFinal) {
    const int n = threadIdx.x;
    const int c = blockIdx.x;
    const float thr = threshes[n];
    float s;
    if (c == 0)      s = acc0[n];
    else if (guess)  s = guess[(size_t)(c-1)*NNEUR + n];
    else             s = 0.0f;

    __shared__ float buf[NNEUR][33];   // +1 pad breaks bank conflicts
    const int tbase = c * CL;

    if (states) {
        for (int t0 = 0; t0 < CL; t0 += 32) {
            for (int tt = 0; tt < 32; ++tt) {
                const int t = tbase + t0 + tt;
                buf[n][tt] = s;                 // pre-state for step t
                float x8[8];
                load_x8(xT, t, x8);
                s = lif_step(s, x8, thr);
            }
            __syncthreads();
#pragma unroll
            for (int i = 0; i < 32; ++i) {      // coalesced flush: 8 rows x 32 cols per iter
                int r  = i*8 + (threadIdx.x >> 5);
                int cc = threadIdx.x & 31;
                states[(size_t)r*TT + tbase + t0 + cc] = buf[r][cc];
            }
            __syncthreads();
        }
    } else {
        for (int tt = 0; tt < CL; ++tt) {
            float x8[8];
            load_x8(xT, tbase + tt, x8);
            s = lif_step(s, x8, thr);
        }
    }
    chunkFinal[(size_t)c*NNEUR + n] = s;
}

// Exact sequential fixup: wave-per-64-neurons, walk chunks carrying the exact state.
__global__ void __launch_bounds__(64) k_fixup(const float* __restrict__ xT,
                                              const float* __restrict__ threshes,
                                              const float* __restrict__ acc0,
                                              const float* __restrict__ finalA,
                                              const float* __restrict__ finalB,
                                              float* __restrict__ states) {
    const int n = blockIdx.x * 64 + threadIdx.x;
    const float thr = threshes[n];
    float s = acc0[n];
    for (int c = 0; c < NC; ++c) {
        float used = (c == 0) ? acc0[n] : finalA[(size_t)(c-1)*NNEUR + n];
        float finB = finalB[(size_t)c*NNEUR + n];
        bool need = (s != used);              // stored chunk exact iff guess matched
        if (__any(need)) {
            const int tbase = c * CL;
            for (int tt = 0; tt < CL; ++tt) {
                const int t = tbase + tt;
                float stored = states[(size_t)n*TT + t];
                if (need && s == stored) need = false;   // merged: rest of chunk is exact
                if (!__any(need)) break;
                if (need) states[(size_t)n*TT + t] = s;  // correct the wrong prefix
                float x8[8];
                load_x8(xT, t, x8);
                float sn = lif_step(s, x8, thr);
                if (need) s = sn;
            }
        }
        s = need ? s : finB;
    }
}

// Output pass: block=(s,b), thread=h; loop n. Coalesced writes; fused loss.
__global__ void __launch_bounds__(256) k_out(const float* __restrict__ in,
                                             const float* __restrict__ threshes,
                                             const float* __restrict__ states,
                                             float* __restrict__ out,
                                             float* __restrict__ gacc) {
    const int h  = threadIdx.x;
    const int s_ = blockIdx.x >> 3;           // 8 consecutive blocks share s_ -> L2 reuse of states
    const int b  = blockIdx.x & 7;
    const int t  = s_ * HH + h;
    const float xv = sigf(in[(size_t)b*TT + t]);
    __shared__ float thrs[NNEUR];
    thrs[h] = threshes[h];
    __syncthreads();

    float* outputs = out;
    float* spikes  = out + OUT1;
    float lossAcc = 0.0f;
    size_t base = ((size_t)(b*SS + s_) * NNEUR) * HH + h;
    for (int n = 0; n < NNEUR; ++n) {
        float st  = states[(size_t)n*TT + t];
        float acc = st + xv;                  // identical op order to lif_step's acc
        bool spike = acc > thrs[n];
        float o = spike ? sigf(acc) : 0.5f;   // sigmoid(0) = 0.5 exactly
        outputs[base + (size_t)n*HH] = o;
        spikes [base + (size_t)n*HH] = spike ? 1.0f : 0.0f;
        lossAcc = fmaf(o, o, lossAcc);
    }
    // norm/N / (B*S*H) contribution, then block-reduce -> one atomic per block
    float v = sqrtf(lossAcc) * (1.0f / (256.0f * 131072.0f));
    for (int off = 32; off > 0; off >>= 1) v += __shfl_down(v, off);
    __shared__ float wsum[4];
    if ((threadIdx.x & 63) == 0) wsum[threadIdx.x >> 6] = v;
    __syncthreads();
    if (threadIdx.x == 0) atomicAdd(gacc, wsum[0] + wsum[1] + wsum[2] + wsum[3]);
}

__global__ void k_final(const float* __restrict__ gacc, const int* __restrict__ dtype,
                        float* __restrict__ lossOut) {
    float g = *gacc;
    *lossOut = (dtype[0] == 1) ? -g : g;
}

extern "C" void kernel_launch(void* const* d_in, const int* in_sizes, int n_in,
                              void* d_out, int out_size, void* d_ws, size_t ws_size,
                              hipStream_t stream) {
    const float* in       = (const float*)d_in[0];
    const float* threshes = (const float*)d_in[1];
    const float* acc0     = (const float*)d_in[2];
    const int*   dtype    = (const int*)d_in[3];
    float* out = (float*)d_out;

    char* ws = (char*)d_ws;
    float* xT     = (float*)(ws);                                   // 524288 B
    float* states = (float*)(ws + 524288);                          // 16777216 B
    float* finalA = (float*)(ws + 524288 + 16777216);               // 131072 B
    float* finalB = (float*)(ws + 524288 + 16777216 + 131072);      // 131072 B
    float* gacc   = (float*)(ws + 524288 + 16777216 + 262144);      // 4 B

    hipMemsetAsync(gacc, 0, 4, stream);
    k_prep <<<TT/256, 256, 0, stream>>>(in, xT);
    k_spec <<<NC, 256, 0, stream>>>(xT, threshes, acc0, nullptr, nullptr, finalA);
    k_spec <<<NC, 256, 0, stream>>>(xT, threshes, acc0, finalA, states, finalB);
    k_fixup<<<NNEUR/64, 64, 0, stream>>>(xT, threshes, acc0, finalA, finalB, states);
    k_out  <<<BB*SS, 256, 0, stream>>>(in, threshes, states, out, gacc);
    k_final<<<1, 1, 0, stream>>>(gacc, dtype, out + 2*OUT1);
}

// Round 2
// 209.956 us; speedup vs baseline: 1.0112x; 1.0112x over previous
//
#include <hip/hip_runtime.h>
#include <math.h>

#define BB 8
#define SS 64
#define HH 256
#define NNEUR 256
#define TT (SS*HH)            // 16384
#define CL 128                // chunk length
#define NC (TT/CL)            // 128 chunks
#define OUT1 ((size_t)BB*SS*NNEUR*HH)   // 33554432

__device__ __forceinline__ float sigf(float v) {
    return 1.0f / (1.0f + expf(-v));
}

// One LIF step: acc_b = s + x_b; spike iff acc_b > thr; new s = max_b(spike ? 0 : acc_b).
// All-spike case falls out naturally (max of zeros = 0). Must be bitwise-identical
// wherever it is used (spec pass, fixup) so float-equality merge detection is valid.
__device__ __forceinline__ float lif_step(float s, const float* __restrict__ x8, float thr) {
    float best = 0.0f;
#pragma unroll
    for (int b = 0; b < BB; ++b) {
        float acc = s + x8[b];
        float cand = (acc > thr) ? 0.0f : acc;
        best = fmaxf(best, cand);
    }
    return best;
}

__device__ __forceinline__ void load_x8(const float* __restrict__ xT, int t, float* x8) {
    const float4* xp = (const float4*)(xT + (size_t)t * 8);
    float4 xa = xp[0], xb = xp[1];
    x8[0]=xa.x; x8[1]=xa.y; x8[2]=xa.z; x8[3]=xa.w;
    x8[4]=xb.x; x8[5]=xb.y; x8[6]=xb.z; x8[7]=xb.w;
}

// Pass 0: x[b][t] = sigmoid(inputs), transposed to xT[t][8] for broadcast reads.
// Thread 0 of block 0 also zeroes the loss accumulator (replaces the 4-byte
// hipMemsetAsync that cost ~156us as a graph fill node).
__global__ void __launch_bounds__(256) k_prep(const float* __restrict__ in, float* __restrict__ xT,
                                              float* __restrict__ gacc) {
    int t = blockIdx.x * 256 + threadIdx.x;
    if (t == 0) *gacc = 0.0f;
    float v[BB];
#pragma unroll
    for (int b = 0; b < BB; ++b) v[b] = sigf(in[(size_t)b*TT + t]);
    float4* o = (float4*)(xT + (size_t)t * 8);
    o[0] = make_float4(v[0], v[1], v[2], v[3]);
    o[1] = make_float4(v[4], v[5], v[6], v[7]);
}

// Speculative chunk scan. block = chunk, thread = neuron.
// Round A: guess==null, states==null -> only chunk finals from guess 0.
// Round B: guess=finalA, states!=null -> store pre-state trajectory [N][T].
__global__ void __launch_bounds__(256) k_spec(const float* __restrict__ xT,
                                              const float* __restrict__ threshes,
                                              const float* __restrict__ acc0,
                                              const float* __restrict__ guess,
                                              float* __restrict__ states,
                                              float* __restrict__ chunkFinal) {
    const int n = threadIdx.x;
    const int c = blockIdx.x;
    const float thr = threshes[n];
    float s;
    if (c == 0)      s = acc0[n];
    else if (guess)  s = guess[(size_t)(c-1)*NNEUR + n];
    else             s = 0.0f;

    __shared__ float buf[NNEUR][33];   // +1 pad breaks bank conflicts
    const int tbase = c * CL;

    if (states) {
        for (int t0 = 0; t0 < CL; t0 += 32) {
            for (int tt = 0; tt < 32; ++tt) {
                const int t = tbase + t0 + tt;
                buf[n][tt] = s;                 // pre-state for step t
                float x8[8];
                load_x8(xT, t, x8);
                s = lif_step(s, x8, thr);
            }
            __syncthreads();
#pragma unroll
            for (int i = 0; i < 32; ++i) {      // coalesced flush: 8 rows x 32 cols per iter
                int r  = i*8 + (threadIdx.x >> 5);
                int cc = threadIdx.x & 31;
                states[(size_t)r*TT + tbase + t0 + cc] = buf[r][cc];
            }
            __syncthreads();
        }
    } else {
        for (int tt = 0; tt < CL; ++tt) {
            float x8[8];
            load_x8(xT, tbase + tt, x8);
            s = lif_step(s, x8, thr);
        }
    }
    chunkFinal[(size_t)c*NNEUR + n] = s;
}

// Exact sequential fixup: wave-per-64-neurons, walk chunks carrying the exact state.
__global__ void __launch_bounds__(64) k_fixup(const float* __restrict__ xT,
                                              const float* __restrict__ threshes,
                                              const float* __restrict__ acc0,
                                              const float* __restrict__ finalA,
                                              const float* __restrict__ finalB,
                                              float* __restrict__ states) {
    const int n = blockIdx.x * 64 + threadIdx.x;
    const float thr = threshes[n];
    float s = acc0[n];
    for (int c = 0; c < NC; ++c) {
        float used = (c == 0) ? acc0[n] : finalA[(size_t)(c-1)*NNEUR + n];
        float finB = finalB[(size_t)c*NNEUR + n];
        bool need = (s != used);              // stored chunk exact iff guess matched
        if (__any(need)) {
            const int tbase = c * CL;
            for (int tt = 0; tt < CL; ++tt) {
                const int t = tbase + tt;
                float stored = states[(size_t)n*TT + t];
                if (need && s == stored) need = false;   // merged: rest of chunk is exact
                if (!__any(need)) break;
                if (need) states[(size_t)n*TT + t] = s;  // correct the wrong prefix
                float x8[8];
                load_x8(xT, t, x8);
                float sn = lif_step(s, x8, thr);
                if (need) s = sn;
            }
        }
        s = need ? s : finB;
    }
}

// Output pass: block=(s,b), thread=h; loop n. Coalesced writes; fused loss.
__global__ void __launch_bounds__(256) k_out(const float* __restrict__ in,
                                             const float* __restrict__ threshes,
                                             const float* __restrict__ states,
                                             float* __restrict__ out,
                                             float* __restrict__ gacc) {
    const int h  = threadIdx.x;
    const int s_ = blockIdx.x >> 3;           // 8 consecutive blocks share s_ -> L2 reuse of states
    const int b  = blockIdx.x & 7;
    const int t  = s_ * HH + h;
    const float xv = sigf(in[(size_t)b*TT + t]);
    __shared__ float thrs[NNEUR];
    thrs[h] = threshes[h];
    __syncthreads();

    float* outputs = out;
    float* spikes  = out + OUT1;
    float lossAcc = 0.0f;
    size_t base = ((size_t)(b*SS + s_) * NNEUR) * HH + h;
    for (int n = 0; n < NNEUR; ++n) {
        float st  = states[(size_t)n*TT + t];
        float acc = st + xv;                  // identical op order to lif_step's acc
        bool spike = acc > thrs[n];
        float o = spike ? sigf(acc) : 0.5f;   // sigmoid(0) = 0.5 exactly
        outputs[base + (size_t)n*HH] = o;
        spikes [base + (size_t)n*HH] = spike ? 1.0f : 0.0f;
        lossAcc = fmaf(o, o, lossAcc);
    }
    // norm/N / (B*S*H) contribution, then block-reduce -> one atomic per block
    float v = sqrtf(lossAcc) * (1.0f / (256.0f * 131072.0f));
    for (int off = 32; off > 0; off >>= 1) v += __shfl_down(v, off);
    __shared__ float wsum[4];
    if ((threadIdx.x & 63) == 0) wsum[threadIdx.x >> 6] = v;
    __syncthreads();
    if (threadIdx.x == 0) atomicAdd(gacc, wsum[0] + wsum[1] + wsum[2] + wsum[3]);
}

__global__ void k_final(const float* __restrict__ gacc, const int* __restrict__ dtype,
                        float* __restrict__ lossOut) {
    float g = *gacc;
    *lossOut = (dtype[0] == 1) ? -g : g;
}

extern "C" void kernel_launch(void* const* d_in, const int* in_sizes, int n_in,
                              void* d_out, int out_size, void* d_ws, size_t ws_size,
                              hipStream_t stream) {
    const float* in       = (const float*)d_in[0];
    const float* threshes = (const float*)d_in[1];
    const float* acc0     = (const float*)d_in[2];
    const int*   dtype    = (const int*)d_in[3];
    float* out = (float*)d_out;

    char* ws = (char*)d_ws;
    float* xT     = (float*)(ws);                                   // 524288 B
    float* states = (float*)(ws + 524288);                          // 16777216 B
    float* finalA = (float*)(ws + 524288 + 16777216);               // 131072 B
    float* finalB = (float*)(ws + 524288 + 16777216 + 131072);      // 131072 B
    float* gacc   = (float*)(ws + 524288 + 16777216 + 262144);      // 4 B

    k_prep <<<TT/256, 256, 0, stream>>>(in, xT, gacc);
    k_spec <<<NC, 256, 0, stream>>>(xT, threshes, acc0, nullptr, nullptr, finalA);
    k_spec <<<NC, 256, 0, stream>>>(xT, threshes, acc0, finalA, states, finalB);
    k_fixup<<<NNEUR/64, 64, 0, stream>>>(xT, threshes, acc0, finalA, finalB, states);
    k_out  <<<BB*SS, 256, 0, stream>>>(in, threshes, states, out, gacc);
    k_final<<<1, 1, 0, stream>>>(gacc, dtype, out + 2*OUT1);
}

// Round 3
// 206.113 us; speedup vs baseline: 1.0301x; 1.0186x over previous
//
#include <hip/hip_runtime.h>
#include <math.h>

#define BB 8
#define SS 64
#define HH 256
#define NNEUR 256
#define TT (SS*HH)            // 16384
#define CL 128                // chunk length
#define NC (TT/CL)            // 128 chunks
#define OUT1 ((size_t)BB*SS*NNEUR*HH)   // 33554432
#define NBLK_OUT (BB*SS)      // 512

__device__ __forceinline__ float sigf(float v) {
    return 1.0f / (1.0f + expf(-v));    // bitwise-critical: feeds spike decisions
}

// One LIF step: acc_b = s + x_b; spike iff acc_b > thr; new s = max_b(spike ? 0 : acc_b).
// Must be bitwise-identical everywhere (spec pass, fixup) so float-equality
// merge detection is valid.
__device__ __forceinline__ float lif_step(float s, const float* __restrict__ x8, float thr) {
    float best = 0.0f;
#pragma unroll
    for (int b = 0; b < BB; ++b) {
        float acc = s + x8[b];
        float cand = (acc > thr) ? 0.0f : acc;
        best = fmaxf(best, cand);
    }
    return best;
}

__device__ __forceinline__ void load_x8(const float* __restrict__ xT, int t, float* x8) {
    const float4* xp = (const float4*)(xT + (size_t)t * 8);
    float4 xa = xp[0], xb = xp[1];
    x8[0]=xa.x; x8[1]=xa.y; x8[2]=xa.z; x8[3]=xa.w;
    x8[4]=xb.x; x8[5]=xb.y; x8[6]=xb.z; x8[7]=xb.w;
}

// Pass 0: x[b][t] = sigmoid(inputs), transposed to xT[t][8]; zero loss acc + ticket.
__global__ void __launch_bounds__(256) k_prep(const float* __restrict__ in, float* __restrict__ xT,
                                              float* __restrict__ gacc, unsigned* __restrict__ ticket) {
    int t = blockIdx.x * 256 + threadIdx.x;
    if (t == 0) { *gacc = 0.0f; *ticket = 0u; }
    float v[BB];
#pragma unroll
    for (int b = 0; b < BB; ++b) v[b] = sigf(in[(size_t)b*TT + t]);
    float4* o = (float4*)(xT + (size_t)t * 8);
    o[0] = make_float4(v[0], v[1], v[2], v[3]);
    o[1] = make_float4(v[4], v[5], v[6], v[7]);
}

// Speculative chunk scan. block = chunk, thread = neuron.
// Round A: guess==null, states==null -> only chunk finals from guess 0.
// Round B: guess=finalA, states!=null -> store pre-state trajectory [N][T].
__global__ void __launch_bounds__(256) k_spec(const float* __restrict__ xT,
                                              const float* __restrict__ threshes,
                                              const float* __restrict__ acc0,
                                              const float* __restrict__ guess,
                                              float* __restrict__ states,
                                              float* __restrict__ chunkFinal) {
    const int n = threadIdx.x;
    const int c = blockIdx.x;
    const float thr = threshes[n];
    float s;
    if (c == 0)      s = acc0[n];
    else if (guess)  s = guess[(size_t)(c-1)*NNEUR + n];
    else             s = 0.0f;

    __shared__ float buf[NNEUR][33];   // +1 pad breaks bank conflicts
    const int tbase = c * CL;

    if (states) {
        for (int t0 = 0; t0 < CL; t0 += 32) {
            for (int tt = 0; tt < 32; ++tt) {
                const int t = tbase + t0 + tt;
                buf[n][tt] = s;                 // pre-state for step t
                float x8[8];
                load_x8(xT, t, x8);
                s = lif_step(s, x8, thr);
            }
            __syncthreads();
#pragma unroll
            for (int i = 0; i < 32; ++i) {      // coalesced flush: 8 rows x 32 cols per iter
                int r  = i*8 + (threadIdx.x >> 5);
                int cc = threadIdx.x & 31;
                states[(size_t)r*TT + tbase + t0 + cc] = buf[r][cc];
            }
            __syncthreads();
        }
    } else {
        for (int tt = 0; tt < CL; ++tt) {
            float x8[8];
            load_x8(xT, tbase + tt, x8);
            s = lif_step(s, x8, thr);
        }
    }
    chunkFinal[(size_t)c*NNEUR + n] = s;
}

// Exact sequential fixup with register double-buffered prefetch of the next
// chunk's finalA/finalB (loads issue before the data-dependent branch of the
// current chunk -> latency overlapped instead of ~700cy exposed per chunk).
__global__ void __launch_bounds__(64) k_fixup(const float* __restrict__ xT,
                                              const float* __restrict__ threshes,
                                              const float* __restrict__ acc0,
                                              const float* __restrict__ finalA,
                                              const float* __restrict__ finalB,
                                              float* __restrict__ states) {
    const int n = blockIdx.x * 64 + threadIdx.x;
    const float thr = threshes[n];
    float s = acc0[n];
    float used_next = acc0[n];                 // "used" guess for chunk 0
    float finB_next = finalB[n];
    for (int c = 0; c < NC; ++c) {
        float used = used_next;
        float finB = finB_next;
        if (c + 1 < NC) {                      // prefetch chunk c+1 inputs NOW
            used_next = finalA[(size_t)c*NNEUR + n];
            finB_next = finalB[(size_t)(c+1)*NNEUR + n];
        }
        bool need = (s != used);              // stored chunk exact iff guess matched
        if (__any(need)) {
            const int tbase = c * CL;
            for (int tt = 0; tt < CL; ++tt) {
                const int t = tbase + tt;
                float stored = states[(size_t)n*TT + t];
                if (need && s == stored) need = false;   // merged: rest of chunk exact
                if (!__any(need)) break;
                if (need) states[(size_t)n*TT + t] = s;  // correct the wrong prefix
                float x8[8];
                load_x8(xT, t, x8);
                float sn = lif_step(s, x8, thr);
                if (need) s = sn;
            }
        }
        s = need ? s : finB;
    }
}

// Output pass: block=(s,b), thread=h; loop n. NT stores (written-once data, keep
// L2 for states); fused loss; last block finalizes the signed loss (ticket).
__global__ void __launch_bounds__(256) k_out(const float* __restrict__ in,
                                             const float* __restrict__ threshes,
                                             const float* __restrict__ states,
                                             float* __restrict__ out,
                                             float* __restrict__ gacc,
                                             unsigned* __restrict__ ticket,
                                             const int* __restrict__ dtype) {
    const int h  = threadIdx.x;
    const int s_ = blockIdx.x >> 3;           // 8 consecutive blocks share s_ -> L2 reuse
    const int b  = blockIdx.x & 7;
    const int t  = s_ * HH + h;
    const float xv = sigf(in[(size_t)b*TT + t]);   // must bitwise-match lif_step's x
    __shared__ float thrs[NNEUR];
    thrs[h] = threshes[h];
    __syncthreads();

    float* outputs = out;
    float* spikes  = out + OUT1;
    float lossAcc = 0.0f;
    size_t base = ((size_t)(b*SS + s_) * NNEUR) * HH + h;
#pragma unroll 4
    for (int n = 0; n < NNEUR; ++n) {
        float st  = states[(size_t)n*TT + t];
        float acc = st + xv;                  // identical op order to lif_step's acc
        bool spike = acc > thrs[n];
        // output sigmoid is NOT decision-feeding -> fast exp is safe (ulp-level diff)
        float o = spike ? (1.0f / (1.0f + __expf(-acc))) : 0.5f;
        __builtin_nontemporal_store(o, &outputs[base + (size_t)n*HH]);
        __builtin_nontemporal_store(spike ? 1.0f : 0.0f, &spikes[base + (size_t)n*HH]);
        lossAcc = fmaf(o, o, lossAcc);
    }
    // norm/N / (B*S*H) contribution, then block-reduce -> one atomic per block
    float v = sqrtf(lossAcc) * (1.0f / (256.0f * 131072.0f));
    for (int off = 32; off > 0; off >>= 1) v += __shfl_down(v, off);
    __shared__ float wsum[4];
    if ((threadIdx.x & 63) == 0) wsum[threadIdx.x >> 6] = v;
    __syncthreads();
    if (threadIdx.x == 0) {
        atomicAdd(gacc, wsum[0] + wsum[1] + wsum[2] + wsum[3]);
        __threadfence();
        unsigned old = atomicAdd(ticket, 1u);
        if (old == NBLK_OUT - 1) {            // last block: finalize signed loss
            __threadfence();
            float g = *(volatile float*)gacc;
            out[2*OUT1] = (dtype[0] == 1) ? -g : g;
        }
    }
}

extern "C" void kernel_launch(void* const* d_in, const int* in_sizes, int n_in,
                              void* d_out, int out_size, void* d_ws, size_t ws_size,
                              hipStream_t stream) {
    const float* in       = (const float*)d_in[0];
    const float* threshes = (const float*)d_in[1];
    const float* acc0     = (const float*)d_in[2];
    const int*   dtype    = (const int*)d_in[3];
    float* out = (float*)d_out;

    char* ws = (char*)d_ws;
    float*    xT     = (float*)(ws);                                   // 524288 B
    float*    states = (float*)(ws + 524288);                          // 16777216 B
    float*    finalA = (float*)(ws + 524288 + 16777216);               // 131072 B
    float*    finalB = (float*)(ws + 524288 + 16777216 + 131072);      // 131072 B
    float*    gacc   = (float*)(ws + 524288 + 16777216 + 262144);      // 4 B
    unsigned* ticket = (unsigned*)(ws + 524288 + 16777216 + 262144 + 4); // 4 B

    k_prep <<<TT/256, 256, 0, stream>>>(in, xT, gacc, ticket);
    k_spec <<<NC, 256, 0, stream>>>(xT, threshes, acc0, nullptr, nullptr, finalA);
    k_spec <<<NC, 256, 0, stream>>>(xT, threshes, acc0, finalA, states, finalB);
    k_fixup<<<NNEUR/64, 64, 0, stream>>>(xT, threshes, acc0, finalA, finalB, states);
    k_out  <<<NBLK_OUT, 256, 0, stream>>>(in, threshes, states, out, gacc, ticket, dtype);
}